// Round 5
// baseline (257.349 us; speedup 1.0000x reference)
//
#include <hip/hip_runtime.h>
#include <math.h>

#define B 256
#define S 50
#define D 32
#define V 10000
#define VPAD 10240
#define KK 16
#define HH 64
#define LL 2
#define UU 32
#define TT 30          // trigger_seq_length
#define NROWS (B*S)    // 12800
#define NORMC 0.01f
#define NCG 40         // code groups (256 codes each, pinned in registers)
#define CPW 256        // codes per wave
#define NTILE 16       // 16x16 B-tiles per wave
#define ROWCH 50       // row chunks
#define RPC 256        // rows per chunk (16 steps x 16 rows)

typedef __attribute__((ext_vector_type(8))) short bf16x8;
typedef __attribute__((ext_vector_type(4))) float f32x4;

__device__ __forceinline__ float sigmoidf_(float x) { return 1.0f / (1.0f + expf(-x)); }

__device__ __forceinline__ unsigned short f2bf(float x) {
    union { float f; unsigned int u; } a; a.f = x;
    unsigned int u = a.u;
    return (unsigned short)((u + 0x7FFFu + ((u >> 16) & 1u)) >> 16);  // RNE, inputs finite
}
__device__ __forceinline__ float bf2f(unsigned short h) {
    union { unsigned int u; float f; } a; a.u = ((unsigned int)h) << 16; return a.f;
}

// ---------------- prep: split fp32 -> (hi,lo) bf16; E padded to VPAD (zeros, tn=+inf);
// Q stores split of NEGATED z1 (MFMA computes tn + (-q).t = tn - q.t). Zero loss.
__global__ __launch_bounds__(256) void k_prep(const float* __restrict__ embd,
                                              const float* __restrict__ z1,
                                              unsigned short* __restrict__ Eh, unsigned short* __restrict__ El,
                                              unsigned short* __restrict__ Qh, unsigned short* __restrict__ Ql,
                                              float* __restrict__ tn, float* __restrict__ loss_sum) {
    int gid = blockIdx.x * 256 + threadIdx.x;
    if (gid == 0) loss_sum[0] = 0.f;
    if (gid >= VPAD * 4 + 4 * NROWS) return;
    int isRow = (gid >= VPAD * 4);
    if (!isRow) {
        int item = gid >> 2, qd = gid & 3;
        unsigned short* dh = Eh + (size_t)item * D + qd * 8;
        unsigned short* dl = El + (size_t)item * D + qd * 8;
        if (item >= V) {   // pad codes: zero embedding, +inf tnorm -> never selected
            unsigned short z[8] = {0, 0, 0, 0, 0, 0, 0, 0};
            *(uint4*)dh = *(const uint4*)z;
            *(uint4*)dl = *(const uint4*)z;
            if (qd == 0) tn[item] = INFINITY;
            return;
        }
        const float* src = embd + (size_t)item * D + qd * 8;
        float4 x0 = *(const float4*)(src);
        float4 x1 = *(const float4*)(src + 4);
        float xs[8] = {x0.x, x0.y, x0.z, x0.w, x1.x, x1.y, x1.z, x1.w};
        unsigned short hv[8], lv[8];
        float ss = 0.f;
#pragma unroll
        for (int i = 0; i < 8; i++) {
            float x = xs[i];
            ss = fmaf(x, x, ss);
            unsigned short h = f2bf(x);
            hv[i] = h;
            lv[i] = f2bf(x - bf2f(h));
        }
        *(uint4*)dh = *(const uint4*)hv;
        *(uint4*)dl = *(const uint4*)lv;
        ss += __shfl_xor(ss, 1);
        ss += __shfl_xor(ss, 2);
        if (qd == 0) tn[item] = 0.5f * ss;
    } else {
        int g = gid - VPAD * 4;
        int item = g >> 2, qd = g & 3;
        const float* src = z1 + (size_t)item * D + qd * 8;
        unsigned short* dh = Qh + (size_t)item * D + qd * 8;
        unsigned short* dl = Ql + (size_t)item * D + qd * 8;
        float4 x0 = *(const float4*)(src);
        float4 x1 = *(const float4*)(src + 4);
        float xs[8] = {x0.x, x0.y, x0.z, x0.w, x1.x, x1.y, x1.z, x1.w};
        unsigned short hv[8], lv[8];
#pragma unroll
        for (int i = 0; i < 8; i++) {
            float x = -xs[i];   // negate
            unsigned short h = f2bf(x);
            hv[i] = h;
            lv[i] = f2bf(x - bf2f(h));
        }
        *(uint4*)dh = *(const uint4*)hv;
        *(uint4*)dl = *(const uint4*)lv;
    }
}

// ---------------- VQ argmin: register-pinned codebook, barrier-free ----------------
// 2000 waves (500 blocks x 4): wave = (cg in 0..39, rc in 0..49). Wave pins 256 codes
// (16 B-tile h/l fragment pairs + tn) in registers, streams 256 rows in 16-row steps.
// Per step: 2 coalesced 16B A-loads, 48 MFMA (ll dropped), compare/shuffle-argmin, store.
__global__ __launch_bounds__(256) void k_vq(const short* __restrict__ Qh, const short* __restrict__ Ql,
                                            const short* __restrict__ Eh, const short* __restrict__ El,
                                            const float* __restrict__ tn,
                                            float2* __restrict__ pbsv) {
    const int tid = threadIdx.x;
    const int lane = tid & 63;
    const int gw = blockIdx.x * 4 + (tid >> 6);
    const int cg = gw % NCG, rc = gw / NCG;
    const int quad = lane >> 4, c15 = lane & 15;
    const int code0 = cg * CPW;
    // pin B fragments: tile i = codes code0+i*16..+15; B[n=c15][k=quad*8+j]
    bf16x8 bh[NTILE], bl[NTILE];
    float tnr[NTILE];
#pragma unroll
    for (int i = 0; i < NTILE; i++) {
        const int code = code0 + i * 16 + c15;
        bh[i] = *(const bf16x8*)(Eh + (size_t)code * 32 + quad * 8);
        bl[i] = *(const bf16x8*)(El + (size_t)code * 32 + quad * 8);
        tnr[i] = tn[code];
    }
    for (int step = 0; step < RPC / 16; step++) {
        const int row0 = rc * RPC + step * 16;
        const bf16x8 ah = *(const bf16x8*)(Qh + (size_t)(row0 + c15) * 32 + quad * 8);
        const bf16x8 al = *(const bf16x8*)(Ql + (size_t)(row0 + c15) * 32 + quad * 8);
        float best[4]; int bestv[4];
#pragma unroll
        for (int e = 0; e < 4; e++) { best[e] = INFINITY; bestv[e] = 0x7fffffff; }
#pragma unroll
        for (int i = 0; i < NTILE; i++) {
            const float t0 = tnr[i];
            f32x4 acc = {t0, t0, t0, t0};
            acc = __builtin_amdgcn_mfma_f32_16x16x32_bf16(ah, bh[i], acc, 0, 0, 0);
            acc = __builtin_amdgcn_mfma_f32_16x16x32_bf16(al, bh[i], acc, 0, 0, 0);
            acc = __builtin_amdgcn_mfma_f32_16x16x32_bf16(ah, bl[i], acc, 0, 0, 0);
            const int v = code0 + i * 16 + c15;   // = output col (C: col=lane&15)
#pragma unroll
            for (int e = 0; e < 4; e++) {
                float s = acc[e];
                if (s < best[e]) { best[e] = s; bestv[e] = v; }   // ascending i => lowest v on ties
            }
        }
        // argmin over the 16 col-lanes (lane bits 0..3); rows = quad*4+e preserved
#pragma unroll
        for (int m = 1; m <= 8; m <<= 1) {
#pragma unroll
            for (int e = 0; e < 4; e++) {
                float os = __shfl_xor(best[e], m);
                int   ov = __shfl_xor(bestv[e], m);
                if (os < best[e] || (os == best[e] && ov < bestv[e])) { best[e] = os; bestv[e] = ov; }
            }
        }
        if (c15 == 0) {
#pragma unroll
            for (int e = 0; e < 4; e++) {
                const int row = row0 + quad * 4 + e;
                float2 p; p.x = best[e]; p.y = __int_as_float(bestv[e]);
                pbsv[(size_t)row * NCG + cg] = p;
            }
        }
    }
}

// ---------------- merge partials, gather z_emb, VQ loss, decoder (s<=TT) ----------------
// 400 blocks x 256 thr; 32 rows/block; 8 lanes/row merge 40 partials + shuffle.
__global__ __launch_bounds__(256) void k_gather(const float* __restrict__ z2,
                                                const float* __restrict__ embd,
                                                const float2* __restrict__ pbsv,
                                                const float* __restrict__ dw1,
                                                const float* __restrict__ db1,
                                                const float* __restrict__ dw2,
                                                const float* __restrict__ db2,
                                                float* __restrict__ z_recon,
                                                float* __restrict__ loss_sum) {
    __shared__ float dw1L[2048];       // [d][h]
    __shared__ float dw2L[2048];       // [h][d]
    __shared__ float db1L[64], db2L[32];
    __shared__ int   vidL[32];
    __shared__ float zeL[32][33];
    __shared__ float aL[32][65];
    const int tid = threadIdx.x;
    const int row0 = blockIdx.x * 32;
    for (int p = tid; p < 2048; p += 256) { dw1L[p] = dw1[p]; dw2L[p] = dw2[p]; }
    if (tid < 64) db1L[tid] = db1[tid];
    if (tid >= 64 && tid < 96) db2L[tid - 64] = db2[tid - 64];
    const int r = tid >> 3, q = tid & 7;
    {   // merge: 8 lanes per row, 5 partials each, then 3 shuffle rounds
        float bs = INFINITY; int bv = 0x7fffffff;
#pragma unroll
        for (int j = 0; j < NCG / 8; j++) {
            float2 p = pbsv[(size_t)(row0 + r) * NCG + j * 8 + q];
            int v = __float_as_int(p.y);
            if (p.x < bs || (p.x == bs && v < bv)) { bs = p.x; bv = v; }
        }
#pragma unroll
        for (int m = 1; m <= 4; m <<= 1) {
            float os = __shfl_xor(bs, m);
            int   ov = __shfl_xor(bv, m);
            if (os < bs || (os == bs && ov < bv)) { bs = os; bv = ov; }
        }
        if (q == 0) vidL[r] = bv;
    }
    __syncthreads();
    {   // fetch z_emb rows
        float4 e4 = *(const float4*)(embd + (size_t)vidL[r] * D + q * 4);
        zeL[r][q * 4 + 0] = e4.x; zeL[r][q * 4 + 1] = e4.y;
        zeL[r][q * 4 + 2] = e4.z; zeL[r][q * 4 + 3] = e4.w;
    }
    __syncthreads();
    {   // loss
        const float* zp = z2 + (size_t)(row0 + r) * D + q * 4;
        float4 x4 = *(const float4*)zp;
        float d0 = x4.x - zeL[r][q * 4 + 0], d1 = x4.y - zeL[r][q * 4 + 1];
        float d2 = x4.z - zeL[r][q * 4 + 2], d3 = x4.w - zeL[r][q * 4 + 3];
        float ls = d0 * d0 + d1 * d1 + d2 * d2 + d3 * d3;
#pragma unroll
        for (int off = 32; off > 0; off >>= 1) ls += __shfl_down(ls, off);
        if ((tid & 63) == 0) atomicAdd(loss_sum, ls);
    }
    const int s = (row0 + r) % S;
    const bool dec = (s <= TT);
    if (dec) {   // phase A: a[r][h], h = q*8..q*8+7
#pragma unroll
        for (int j = 0; j < 8; j++) {
            int h = q * 8 + j;
            float a = db1L[h];
#pragma unroll
            for (int d = 0; d < 32; d++) a = fmaf(zeL[r][d], dw1L[d * 64 + h], a);
            aL[r][h] = (a >= 0.f) ? a : 0.1f * a;
        }
    }
    __syncthreads();
    if (dec) {   // phase B: zr[d], d = q*4..q*4+3
        const int b = (row0 + r) / S;
        float zr[4];
#pragma unroll
        for (int dd = 0; dd < 4; dd++) zr[dd] = db2L[q * 4 + dd];
        for (int h = 0; h < 64; h++) {
            float av = aL[r][h];
#pragma unroll
            for (int dd = 0; dd < 4; dd++) zr[dd] = fmaf(av, dw2L[h * 32 + q * 4 + dd], zr[dd]);
        }
        float4 o4 = make_float4(zr[0], zr[1], zr[2], zr[3]);
        *(float4*)(z_recon + (size_t)b * ((TT + 1) * D) + s * D + q * 4) = o4;
    }
}

// ---------------- GRU (31 steps) + output MLP; 512 blocks: [gru][sample] ----------------
__global__ __launch_bounds__(128) void k_gru(const float* __restrict__ z_recon,
                                             const float* __restrict__ z2,
                                             const float* __restrict__ i_wih, const float* __restrict__ i_whh,
                                             const float* __restrict__ i_bih, const float* __restrict__ i_bhh,
                                             const float* __restrict__ c_wih, const float* __restrict__ c_whh,
                                             const float* __restrict__ c_bih, const float* __restrict__ c_bhh,
                                             const float* __restrict__ im_w1, const float* __restrict__ im_b1,
                                             const float* __restrict__ im_w2, const float* __restrict__ im_b2,
                                             const float* __restrict__ cm_w1, const float* __restrict__ cm_b1,
                                             const float* __restrict__ cm_w2, const float* __restrict__ cm_b2,
                                             float* __restrict__ z1f, float* __restrict__ z2f) {
    const int tid = threadIdx.x;
    const int which = blockIdx.x >> 8;
    const int b = blockIdx.x & 255;
    const float* x; int xstride;
    const float *wih, *whh, *bih, *bhh, *w1, *b1, *w2, *b2; float* zf;
    if (which == 0) { x = z_recon; xstride = (TT + 1) * D; wih = i_wih; whh = i_whh; bih = i_bih; bhh = i_bhh; w1 = im_w1; b1 = im_b1; w2 = im_w2; b2 = im_b2; zf = z1f; }
    else            { x = z2;      xstride = S * D;        wih = c_wih; whh = c_whh; bih = c_bih; bhh = c_bhh; w1 = cm_w1; b1 = cm_b1; w2 = cm_w2; b2 = cm_b2; zf = z2f; }
    __shared__ float wihT[32][97];
    __shared__ float whhT[32][97];
    __shared__ float gi[TT + 1][96];
    __shared__ float xs[TT + 1][32];
    __shared__ float hsh[2][32];
    __shared__ float gh[96];
    __shared__ float bh2[96];
    __shared__ float af[32];
    for (int p = tid; p < 96 * 32; p += 128) {
        int e = p >> 5, d = p & 31;
        wihT[d][e] = wih[p];
        whhT[d][e] = whh[p];
    }
    for (int p = tid; p < (TT + 1) * D; p += 128) xs[p >> 5][p & 31] = x[(size_t)b * xstride + p];
    if (tid < 96) bh2[tid] = bhh[tid];
    if (tid < 32) hsh[0][tid] = 0.f;
    __syncthreads();
    for (int p = tid; p < (TT + 1) * 96; p += 128) {
        int s = p / 96, e = p % 96;
        float g0 = bih[e], g1 = 0.f;
#pragma unroll
        for (int d = 0; d < 16; d++) g0 = fmaf(xs[s][d], wihT[d][e], g0);
#pragma unroll
        for (int d = 16; d < 32; d++) g1 = fmaf(xs[s][d], wihT[d][e], g1);
        gi[s][e] = g0 + g1;
    }
    __syncthreads();
    for (int t = 0; t <= TT; t++) {
        const int cur = t & 1;
        if (tid < 96) {
            float g0 = bh2[tid], g1 = 0.f;
#pragma unroll
            for (int d = 0; d < 16; d++) g0 = fmaf(hsh[cur][d], whhT[d][tid], g0);
#pragma unroll
            for (int d = 16; d < 32; d++) g1 = fmaf(hsh[cur][d], whhT[d][tid], g1);
            gh[tid] = g0 + g1;
        }
        __syncthreads();
        if (tid < 32) {
            float rr = sigmoidf_(gi[t][tid] + gh[tid]);
            float zz = sigmoidf_(gi[t][tid + 32] + gh[tid + 32]);
            float nn = tanhf(gi[t][tid + 64] + rr * gh[tid + 64]);
            hsh[1 - cur][tid] = (1.f - zz) * nn + zz * hsh[cur][tid];
        }
        __syncthreads();
    }
    if (tid < 32) {
        float a = b1[tid];
#pragma unroll
        for (int d = 0; d < 32; d++) a = fmaf(hsh[1][d], w1[d * 32 + tid], a);
        af[tid] = tanhf(a);
    }
    __syncthreads();
    if (tid < 32) {
        float o = b2[tid];
#pragma unroll
        for (int d = 0; d < 32; d++) o = fmaf(af[d], w2[d * 32 + tid], o);
        zf[(size_t)b * 32 + tid] = o;
    }
}

// ---------------- hypernet weight-gen ----------------
__global__ __launch_bounds__(256) void k_wgen(const float* __restrict__ z1f_, const float* __restrict__ z2f_,
                                              const float* __restrict__ hw1, const float* __restrict__ hb1,
                                              const float* __restrict__ hw2, const float* __restrict__ hb2,
                                              float* __restrict__ w_out) {
    __shared__ float z1s[32], z2s[32];
    const int tid = threadIdx.x;
    const int b = blockIdx.x >> 1;
    const int layer = blockIdx.x & 1;
    if (tid < 32) z1s[tid] = z1f_[b * 32 + tid];
    else if (tid < 64) z2s[tid - 32] = z2f_[b * 32 + tid - 32];
    __syncthreads();
    const int kk = tid;
    const float* h1 = hw1 + layer * 8192 + kk;
    const float* h2 = hw2 + layer * 8192 + kk;
    float a = hb1[layer * 256 + kk];
    float c = hb2[layer * 256 + kk];
#pragma unroll
    for (int d = 0; d < 32; d++) {
        a = fmaf(z1s[d], h1[d * 256], a);
        c = fmaf(z2s[d], h2[d * 256], c);
    }
    a = fminf(fmaxf(a, -NORMC), NORMC);
    w_out[(size_t)b * 512 + layer * 256 + kk] = a + c;
}

// ---------------- apply + loss write ----------------
__global__ __launch_bounds__(256) void k_apply(const float* __restrict__ x1,
                                               const float* __restrict__ w_in,
                                               const float* __restrict__ lin_w, const float* __restrict__ lin_b,
                                               const float* __restrict__ lout_w, const float* __restrict__ lout_b,
                                               const float* __restrict__ loss_sum, float* __restrict__ out) {
    __shared__ float linw[1024], loutw[1024], linb[32], loutb[64];
    __shared__ float wL[8][512];
    __shared__ float oc[8][32], t1s[8][16], t2s[8][16];
    const int tid = threadIdx.x;
    const int b0 = blockIdx.x * 8;
    {
        for (int p = tid; p < 1024; p += 256) { linw[p] = lin_w[p]; loutw[p] = lout_w[p]; }
        if (tid < 32) linb[tid] = lin_b[tid];
        if (tid >= 32 && tid < 96) loutb[tid - 32] = lout_b[tid - 32];
        const float4* src = (const float4*)(w_in + (size_t)b0 * 512);
#pragma unroll
        for (int i = 0; i < 4; i++) {
            float4 v = src[tid + i * 256];
            ((float4*)&wL[0][0])[tid + i * 256] = v;
        }
        float v = x1[b0 * 32 + tid];
        oc[tid >> 5][tid & 31] = v;
    }
    __syncthreads();
    const int s = tid >> 5, l = tid & 31;
#pragma unroll
    for (int i = 0; i < LL; i++) {
        if (l < 16) {
            float a = linb[i * 16 + l];
#pragma unroll
            for (int u = 0; u < 32; u++) a = fmaf(oc[s][u], linw[i * 512 + u * 16 + l], a);
            t1s[s][l] = a;
        }
        __syncthreads();
        if (l < 16) {
            float a = 0.f;
#pragma unroll
            for (int k = 0; k < 16; k++) a = fmaf(t1s[s][k], wL[s][i * 256 + k * 16 + l], a);
            t2s[s][l] = a;
        }
        __syncthreads();
        {
            float a = loutb[i * 32 + l];
#pragma unroll
            for (int k = 0; k < 16; k++) a = fmaf(t2s[s][k], loutw[i * 512 + k * 32 + l], a);
            oc[s][l] = a;
        }
        __syncthreads();
    }
    out[(size_t)(b0 + s) * 32 + l] = oc[s][l];
    if (blockIdx.x == 0 && tid == 0) out[B * UU] = loss_sum[0] * (1.0f / (float)(B * S * D));
}

extern "C" void kernel_launch(void* const* d_in, const int* in_sizes, int n_in,
                              void* d_out, int out_size, void* d_ws, size_t ws_size,
                              hipStream_t stream) {
    const float* x1     = (const float*)d_in[0];
    const float* z1     = (const float*)d_in[1];
    const float* z2     = (const float*)d_in[3];
    const float* embd   = (const float*)d_in[4];
    const float* dec_w1 = (const float*)d_in[5];
    const float* dec_b1 = (const float*)d_in[6];
    const float* dec_w2 = (const float*)d_in[7];
    const float* dec_b2 = (const float*)d_in[8];
    const float* i_wih  = (const float*)d_in[9];
    const float* i_whh  = (const float*)d_in[10];
    const float* i_bih  = (const float*)d_in[11];
    const float* i_bhh  = (const float*)d_in[12];
    const float* c_wih  = (const float*)d_in[13];
    const float* c_whh  = (const float*)d_in[14];
    const float* c_bih  = (const float*)d_in[15];
    const float* c_bhh  = (const float*)d_in[16];
    const float* im_w1  = (const float*)d_in[17];
    const float* im_b1  = (const float*)d_in[18];
    const float* im_w2  = (const float*)d_in[19];
    const float* im_b2  = (const float*)d_in[20];
    const float* cm_w1  = (const float*)d_in[21];
    const float* cm_b1  = (const float*)d_in[22];
    const float* cm_w2  = (const float*)d_in[23];
    const float* cm_b2  = (const float*)d_in[24];
    const float* hw1    = (const float*)d_in[25];
    const float* hb1    = (const float*)d_in[26];
    const float* hw2    = (const float*)d_in[27];
    const float* hb2    = (const float*)d_in[28];
    const float* lin_w  = (const float*)d_in[29];
    const float* lin_b  = (const float*)d_in[30];
    const float* lout_w = (const float*)d_in[31];
    const float* lout_b = (const float*)d_in[32];

    // workspace layout (floats)
    float* wsf      = (float*)d_ws;
    float* loss_sum = wsf;                        // pad 64
    float* tn       = wsf + 64;                   // VPAD -> 10304
    float2* pbsv    = (float2*)(wsf + 10304);     // NROWS*NCG float2 = 1024000 f -> 1034304
    unsigned short* Eh = (unsigned short*)(wsf + 1034304);  // VPAD*32 shorts = 163840 f -> 1198144
    unsigned short* El = (unsigned short*)(wsf + 1198144);  // -> 1361984
    unsigned short* Qh = (unsigned short*)(wsf + 1361984);  // NROWS*32 shorts = 204800 f -> 1566784
    unsigned short* Ql = (unsigned short*)(wsf + 1566784);  // -> 1771584
    float* z1f      = wsf + 1771584;              // 8192 -> 1779776
    float* z2f      = wsf + 1779776;              // 8192 -> 1787968 (~7.2 MB)
    float* z_recon  = (float*)Eh;                 // 253952 f, aliases Eh/El (dead after k_vq)
    float* w_out    = (float*)Qh;                 // 131072 f, aliases Qh (dead after k_vq)

    k_prep<<<(VPAD * 4 + 4 * NROWS + 255) / 256, 256, 0, stream>>>(embd, z1, Eh, El, Qh, Ql, tn, loss_sum);
    k_vq<<<(NCG * ROWCH) / 4, 256, 0, stream>>>((const short*)Qh, (const short*)Ql,
                                                (const short*)Eh, (const short*)El, tn, pbsv);
    k_gather<<<NROWS / 32, 256, 0, stream>>>(z2, embd, pbsv, dec_w1, dec_b1,
                                             dec_w2, dec_b2, z_recon, loss_sum);
    k_gru<<<512, 128, 0, stream>>>(z_recon, z2, i_wih, i_whh, i_bih, i_bhh,
                                   c_wih, c_whh, c_bih, c_bhh,
                                   im_w1, im_b1, im_w2, im_b2,
                                   cm_w1, cm_b1, cm_w2, cm_b2, z1f, z2f);
    k_wgen<<<2 * B, 256, 0, stream>>>(z1f, z2f, hw1, hb1, hw2, hb2, w_out);
    k_apply<<<B / 8, 256, 0, stream>>>(x1, w_out, lin_w, lin_b, lout_w, lout_b,
                                       loss_sum, (float*)d_out);
}

// Round 6
// 196.695 us; speedup vs baseline: 1.3084x; 1.3084x over previous
//
#include <hip/hip_runtime.h>
#include <math.h>

#define B 256
#define S 50
#define D 32
#define V 10000
#define VPAD 10240
#define KK 16
#define HH 64
#define LL 2
#define UU 32
#define TT 30          // trigger_seq_length
#define NROWS (B*S)    // 12800
#define NORMC 0.01f
#define CH 256         // codes per LDS chunk in k_vq
#define NSLICE 10
#define SLICE_V 1024   // VPAD / NSLICE
#define VQ_RB 128      // rows per k_vq block

typedef __attribute__((ext_vector_type(8))) short bf16x8;
typedef __attribute__((ext_vector_type(4))) float f32x4;

__device__ __forceinline__ float sigmoidf_(float x) { return 1.0f / (1.0f + expf(-x)); }

__device__ __forceinline__ unsigned short f2bf(float x) {
    union { float f; unsigned int u; } a; a.f = x;
    unsigned int u = a.u;
    return (unsigned short)((u + 0x7FFFu + ((u >> 16) & 1u)) >> 16);  // RNE, inputs finite
}
__device__ __forceinline__ float bf2f(unsigned short h) {
    union { unsigned int u; float f; } a; a.u = ((unsigned int)h) << 16; return a.f;
}

__device__ __forceinline__ void gld16(void* lds, const void* g) {
    __builtin_amdgcn_global_load_lds(
        (const __attribute__((address_space(1))) unsigned int*)g,
        (__attribute__((address_space(3))) unsigned int*)lds, 16, 0, 0);
}
__device__ __forceinline__ void gld4(void* lds, const void* g) {
    __builtin_amdgcn_global_load_lds(
        (const __attribute__((address_space(1))) unsigned int*)g,
        (__attribute__((address_space(3))) unsigned int*)lds, 4, 0, 0);
}

// ---------------- prep: split fp32 -> (hi,lo) bf16; E padded to VPAD (zeros, tn=+inf);
// Q stores split of NEGATED z1 (MFMA computes tn - q.t). Zero loss + ticket counter.
__global__ __launch_bounds__(256) void k_prep(const float* __restrict__ embd,
                                              const float* __restrict__ z1,
                                              unsigned short* __restrict__ Eh, unsigned short* __restrict__ El,
                                              unsigned short* __restrict__ Qh, unsigned short* __restrict__ Ql,
                                              float* __restrict__ tn, float* __restrict__ loss_sum,
                                              unsigned int* __restrict__ cnt) {
    int gid = blockIdx.x * 256 + threadIdx.x;
    if (gid == 0) loss_sum[0] = 0.f;
    if (gid == 1) cnt[0] = 0u;
    if (gid >= VPAD * 4 + 4 * NROWS) return;
    int isRow = (gid >= VPAD * 4);
    if (!isRow) {
        int item = gid >> 2, qd = gid & 3;
        unsigned short* dh = Eh + (size_t)item * D + qd * 8;
        unsigned short* dl = El + (size_t)item * D + qd * 8;
        if (item >= V) {
            unsigned short z[8] = {0, 0, 0, 0, 0, 0, 0, 0};
            *(uint4*)dh = *(const uint4*)z;
            *(uint4*)dl = *(const uint4*)z;
            if (qd == 0) tn[item] = INFINITY;
            return;
        }
        const float* src = embd + (size_t)item * D + qd * 8;
        float4 x0 = *(const float4*)(src);
        float4 x1 = *(const float4*)(src + 4);
        float xs[8] = {x0.x, x0.y, x0.z, x0.w, x1.x, x1.y, x1.z, x1.w};
        unsigned short hv[8], lv[8];
        float ss = 0.f;
#pragma unroll
        for (int i = 0; i < 8; i++) {
            float x = xs[i];
            ss = fmaf(x, x, ss);
            unsigned short h = f2bf(x);
            hv[i] = h;
            lv[i] = f2bf(x - bf2f(h));
        }
        *(uint4*)dh = *(const uint4*)hv;
        *(uint4*)dl = *(const uint4*)lv;
        ss += __shfl_xor(ss, 1);
        ss += __shfl_xor(ss, 2);
        if (qd == 0) tn[item] = 0.5f * ss;
    } else {
        int g = gid - VPAD * 4;
        int item = g >> 2, qd = g & 3;
        const float* src = z1 + (size_t)item * D + qd * 8;
        unsigned short* dh = Qh + (size_t)item * D + qd * 8;
        unsigned short* dl = Ql + (size_t)item * D + qd * 8;
        float4 x0 = *(const float4*)(src);
        float4 x1 = *(const float4*)(src + 4);
        float xs[8] = {x0.x, x0.y, x0.z, x0.w, x1.x, x1.y, x1.z, x1.w};
        unsigned short hv[8], lv[8];
#pragma unroll
        for (int i = 0; i < 8; i++) {
            float x = -xs[i];
            unsigned short h = f2bf(x);
            hv[i] = h;
            lv[i] = f2bf(x - bf2f(h));
        }
        *(uint4*)dh = *(const uint4*)hv;
        *(uint4*)dl = *(const uint4*)lv;
    }
}

// ---------------- VQ argmin via split-bf16 MFMA (hh+lh+hl), XOR-swizzled LDS ----------------
// Grid: 100 row-groups (128 rows) x 10 V-slices (1024 codes). Block 256 thr = 4 waves.
__global__ __launch_bounds__(256, 4) void k_vq(const short* __restrict__ Qh, const short* __restrict__ Ql,
                                               const short* __restrict__ Eh, const short* __restrict__ El,
                                               const float* __restrict__ tn,
                                               float2* __restrict__ pbsv) {
    __shared__ __attribute__((aligned(16))) short EhL[CH * 32];  // 16 KB
    __shared__ __attribute__((aligned(16))) short ElL[CH * 32];  // 16 KB
    __shared__ float tnL[CH];
    const int tid = threadIdx.x;
    const int wave = tid >> 6, lane = tid & 63;
    const int rg = blockIdx.x / NSLICE, slice = blockIdx.x % NSLICE;
    const int row0 = rg * VQ_RB;
    const int quad = lane >> 4, c15 = lane & 15;
    const int swz = quad ^ ((c15 >> 1) & 3);            // reader swizzle (16B units)
    const int ar0 = row0 + wave * 32 + c15;
    bf16x8 ah0 = *(const bf16x8*)(Qh + (size_t)ar0 * 32 + quad * 8);
    bf16x8 al0 = *(const bf16x8*)(Ql + (size_t)ar0 * 32 + quad * 8);
    bf16x8 ah1 = *(const bf16x8*)(Qh + (size_t)(ar0 + 16) * 32 + quad * 8);
    bf16x8 al1 = *(const bf16x8*)(Ql + (size_t)(ar0 + 16) * 32 + quad * 8);
    float best0[4], best1[4]; int bv0[4], bv1[4];
#pragma unroll
    for (int i = 0; i < 4; i++) {
        best0[i] = INFINITY; best1[i] = INFINITY;
        bv0[i] = 0x7fffffff; bv1[i] = 0x7fffffff;
    }
    const int vbeg = slice * SLICE_V;
    for (int c0 = 0; c0 < SLICE_V; c0 += CH) {
        __syncthreads();
        {   // stage 256 codes, swizzled within 64B rows
            const int sbS = (vbeg + c0) * 32;  // shorts
#pragma unroll
            for (int i = 0; i < 4; i++) {
                int c = wave * 256 + i * 64 + lane;
                int code = c >> 2;
                int q = (c & 3) ^ ((c >> 3) & 3);
                int srcOff = sbS + code * 32 + q * 8;
                int dstOff = (wave * 256 + i * 64) * 8;
                gld16(EhL + dstOff, Eh + srcOff);
                gld16(ElL + dstOff, El + srcOff);
            }
            gld4(tnL + wave * 64, tn + vbeg + c0 + wave * 64 + lane);
        }
        __syncthreads();
#pragma unroll
        for (int t = 0; t < 16; t++) {
            const int code = t * 16 + c15;
            const int boff = code * 32 + swz * 8;
            bf16x8 bh = *(const bf16x8*)(EhL + boff);
            bf16x8 bl = *(const bf16x8*)(ElL + boff);
            const float tnv = tnL[code];
            f32x4 acc0 = {tnv, tnv, tnv, tnv};
            f32x4 acc1 = {tnv, tnv, tnv, tnv};
            acc0 = __builtin_amdgcn_mfma_f32_16x16x32_bf16(ah0, bh, acc0, 0, 0, 0);
            acc1 = __builtin_amdgcn_mfma_f32_16x16x32_bf16(ah1, bh, acc1, 0, 0, 0);
            acc0 = __builtin_amdgcn_mfma_f32_16x16x32_bf16(al0, bh, acc0, 0, 0, 0);
            acc1 = __builtin_amdgcn_mfma_f32_16x16x32_bf16(al1, bh, acc1, 0, 0, 0);
            acc0 = __builtin_amdgcn_mfma_f32_16x16x32_bf16(ah0, bl, acc0, 0, 0, 0);
            acc1 = __builtin_amdgcn_mfma_f32_16x16x32_bf16(ah1, bl, acc1, 0, 0, 0);
            const int v = vbeg + c0 + code;             // pad codes carry tn=+inf
#pragma unroll
            for (int i = 0; i < 4; i++) {
                float s0 = acc0[i];
                if (s0 < best0[i]) { best0[i] = s0; bv0[i] = v; }
                float s1 = acc1[i];
                if (s1 < best1[i]) { best1[i] = s1; bv1[i] = v; }
            }
        }
    }
#pragma unroll
    for (int m = 1; m <= 8; m <<= 1) {
#pragma unroll
        for (int i = 0; i < 4; i++) {
            float os = __shfl_xor(best0[i], m); int ov = __shfl_xor(bv0[i], m);
            if (os < best0[i] || (os == best0[i] && ov < bv0[i])) { best0[i] = os; bv0[i] = ov; }
            os = __shfl_xor(best1[i], m); ov = __shfl_xor(bv1[i], m);
            if (os < best1[i] || (os == best1[i] && ov < bv1[i])) { best1[i] = os; bv1[i] = ov; }
        }
    }
    if (c15 == 0) {
#pragma unroll
        for (int i = 0; i < 4; i++) {
            int r0 = row0 + wave * 32 + quad * 4 + i;
            float2 p0; p0.x = best0[i]; p0.y = __int_as_float(bv0[i]);
            pbsv[(size_t)r0 * NSLICE + slice] = p0;
            int r1 = r0 + 16;
            float2 p1; p1.x = best1[i]; p1.y = __int_as_float(bv1[i]);
            pbsv[(size_t)r1 * NSLICE + slice] = p1;
        }
    }
}

// ---------------- fused: merge + gather + loss + decoder + 2xGRU + MLPs + wgen + apply ----
// One block per sample (256 blocks x 256 thr = 1 block/CU).
__global__ __launch_bounds__(256) void k_fused(
        const float* __restrict__ x1, const float* __restrict__ z2,
        const float* __restrict__ embd, const float2* __restrict__ pbsv,
        const float* __restrict__ dw1, const float* __restrict__ db1,
        const float* __restrict__ dw2, const float* __restrict__ db2,
        const float* __restrict__ i_wih, const float* __restrict__ i_whh,
        const float* __restrict__ i_bih, const float* __restrict__ i_bhh,
        const float* __restrict__ c_wih, const float* __restrict__ c_whh,
        const float* __restrict__ c_bih, const float* __restrict__ c_bhh,
        const float* __restrict__ im_w1, const float* __restrict__ im_b1,
        const float* __restrict__ im_w2, const float* __restrict__ im_b2,
        const float* __restrict__ cm_w1, const float* __restrict__ cm_b1,
        const float* __restrict__ cm_w2, const float* __restrict__ cm_b2,
        const float* __restrict__ hw1, const float* __restrict__ hb1,
        const float* __restrict__ hw2, const float* __restrict__ hb2,
        const float* __restrict__ lin_w, const float* __restrict__ lin_b,
        const float* __restrict__ lout_w, const float* __restrict__ lout_b,
        float* __restrict__ loss_sum, unsigned int* __restrict__ cnt,
        float* __restrict__ out) {
    __shared__ float zeL[50][33];                    // 6.6 KB
    __shared__ float dw1L[2048], dw2L[2048];         // 16 KB
    __shared__ float db1L[64], db2L[32];
    __shared__ __attribute__((aligned(16))) float xsi[TT + 1][32];   // decoder out = GRU-i input
    __shared__ float gii[TT + 1][96], gic[TT + 1][96];               // 23.8 KB
    __shared__ float aL[TT + 1][65];                 // 8.1 KB
    __shared__ __attribute__((aligned(16))) float hI[2][32], hC[2][32];
    __shared__ float ghI[96], ghC[96];
    __shared__ float afL[2][32];
    __shared__ float z1fL[32], z2fL[32];
    __shared__ float wW[512];
    __shared__ float t1s[16], t2s[16], ocs[32];
    __shared__ int   vidL[50];
    __shared__ float lossRed[4];
    const int tid = threadIdx.x;
    const int b = blockIdx.x;
    const float* z2b = z2 + (size_t)b * (S * D);

    // P0: stage decoder weights; merge VQ partials
    for (int p = tid; p < 2048; p += 256) { dw1L[p] = dw1[p]; dw2L[p] = dw2[p]; }
    if (tid < 64) db1L[tid] = db1[tid];
    if (tid >= 64 && tid < 96) db2L[tid - 64] = db2[tid - 64];
    if (tid < 50) {
        const float2* pp = pbsv + (size_t)(b * S + tid) * NSLICE;
        float bs = INFINITY; int bv = 0x7fffffff;
#pragma unroll
        for (int j = 0; j < NSLICE; j++) {
            float2 p = pp[j];
            int v = __float_as_int(p.y);
            if (p.x < bs) { bs = p.x; bv = v; }   // ascending slice => lowest v on ties
        }
        vidL[tid] = bv;
    }
    __syncthreads();
    // P1: fetch z_emb rows
    {
        const int q = tid & 7;
#pragma unroll
        for (int it = 0; it < 2; it++) {
            int s = it * 32 + (tid >> 3);
            if (s < 50) {
                float4 e4 = *(const float4*)(embd + (size_t)vidL[s] * D + q * 4);
                zeL[s][q * 4 + 0] = e4.x; zeL[s][q * 4 + 1] = e4.y;
                zeL[s][q * 4 + 2] = e4.z; zeL[s][q * 4 + 3] = e4.w;
            }
        }
    }
    __syncthreads();
    // P2: loss partial + decoder phase A
    {
        const int q = tid & 7;
        float ls = 0.f;
#pragma unroll
        for (int it = 0; it < 2; it++) {
            int s = it * 32 + (tid >> 3);
            if (s < 50) {
                float4 x4 = *(const float4*)(z2b + s * D + q * 4);
                float d0 = x4.x - zeL[s][q * 4 + 0], d1 = x4.y - zeL[s][q * 4 + 1];
                float d2 = x4.z - zeL[s][q * 4 + 2], d3 = x4.w - zeL[s][q * 4 + 3];
                ls += d0 * d0 + d1 * d1 + d2 * d2 + d3 * d3;
            }
        }
#pragma unroll
        for (int off = 32; off > 0; off >>= 1) ls += __shfl_down(ls, off);
        if ((tid & 63) == 0) lossRed[tid >> 6] = ls;
        const int s = tid >> 3;
        if (s <= TT) {
#pragma unroll
            for (int j = 0; j < 8; j++) {
                int h = q * 8 + j;
                float a = db1L[h];
#pragma unroll
                for (int d = 0; d < 32; d++) a = fmaf(zeL[s][d], dw1L[d * 64 + h], a);
                aL[s][h] = (a >= 0.f) ? a : 0.1f * a;
            }
        }
    }
    __syncthreads();
    // P3: decoder phase B -> xsi ; block loss atomic
    if (tid == 0) atomicAdd(loss_sum, lossRed[0] + lossRed[1] + lossRed[2] + lossRed[3]);
    {
        const int s = tid >> 3, q = tid & 7;
        if (s <= TT) {
            float zr[4];
#pragma unroll
            for (int dd = 0; dd < 4; dd++) zr[dd] = db2L[q * 4 + dd];
            for (int h = 0; h < 64; h++) {
                float av = aL[s][h];
#pragma unroll
                for (int dd = 0; dd < 4; dd++) zr[dd] = fmaf(av, dw2L[h * 32 + q * 4 + dd], zr[dd]);
            }
            float4 o4 = make_float4(zr[0], zr[1], zr[2], zr[3]);
            *(float4*)&xsi[s][q * 4] = o4;
        }
    }
    __syncthreads();
    // GRU lane mapping: waves 0-1 lanes 0..95 -> GRU-i (e=tid); waves 2-3 lanes 128..223 -> GRU-c
    const bool actG = (tid < 96) || (tid >= 128 && tid < 224);
    const int gru = (tid >= 128) ? 1 : 0;
    const int e = gru ? (tid - 128) : tid;
    // P4: gi precompute (wih row pinned in VGPRs)
    if (actG) {
        float wihRow[32];
        const float* wg = gru ? c_wih : i_wih;
#pragma unroll
        for (int d = 0; d < 32; d++) wihRow[d] = wg[e * 32 + d];
        const float bi = (gru ? c_bih : i_bih)[e];
        float* giP = gru ? &gic[0][0] : &gii[0][0];
        for (int s = 0; s <= TT; s++) {
            float g = bi;
            if (gru) {
                const float4* xp = (const float4*)(z2b + s * D);
#pragma unroll
                for (int k = 0; k < 8; k++) {
                    float4 xv = xp[k];
                    g = fmaf(xv.x, wihRow[4 * k + 0], g);
                    g = fmaf(xv.y, wihRow[4 * k + 1], g);
                    g = fmaf(xv.z, wihRow[4 * k + 2], g);
                    g = fmaf(xv.w, wihRow[4 * k + 3], g);
                }
            } else {
                const float4* xp = (const float4*)&xsi[s][0];
#pragma unroll
                for (int k = 0; k < 8; k++) {
                    float4 xv = xp[k];
                    g = fmaf(xv.x, wihRow[4 * k + 0], g);
                    g = fmaf(xv.y, wihRow[4 * k + 1], g);
                    g = fmaf(xv.z, wihRow[4 * k + 2], g);
                    g = fmaf(xv.w, wihRow[4 * k + 3], g);
                }
            }
            giP[s * 96 + e] = g;
        }
    }
    // pin whh row + init h
    float whhRow[32]; float bh = 0.f;
    if (actG) {
        const float* wg = gru ? c_whh : i_whh;
#pragma unroll
        for (int d = 0; d < 32; d++) whhRow[d] = wg[e * 32 + d];
        bh = (gru ? c_bhh : i_bhh)[e];
    }
    if (tid < 64) { (tid < 32 ? hI[0] : hC[0])[tid & 31] = 0.f; }
    __syncthreads();
    // P5: recurrent loop
    for (int t = 0; t <= TT; t++) {
        const int cur = t & 1;
        if (actG) {
            float g = bh;
            const float4* hp = (const float4*)(gru ? &hC[cur][0] : &hI[cur][0]);
#pragma unroll
            for (int k = 0; k < 8; k++) {
                float4 hv = hp[k];
                g = fmaf(hv.x, whhRow[4 * k + 0], g);
                g = fmaf(hv.y, whhRow[4 * k + 1], g);
                g = fmaf(hv.z, whhRow[4 * k + 2], g);
                g = fmaf(hv.w, whhRow[4 * k + 3], g);
            }
            (gru ? ghC : ghI)[e] = g;
        }
        __syncthreads();
        if (tid < 64) {
            const int g2 = tid >> 5, l = tid & 31;
            const float* giP = g2 ? &gic[t][0] : &gii[t][0];
            const float* ghP = g2 ? ghC : ghI;
            float* hP = g2 ? &hC[0][0] : &hI[0][0];
            float rr = sigmoidf_(giP[l] + ghP[l]);
            float zz = sigmoidf_(giP[l + 32] + ghP[l + 32]);
            float nn = tanhf(giP[l + 64] + rr * ghP[l + 64]);
            hP[(1 - cur) * 32 + l] = (1.f - zz) * nn + zz * hP[cur * 32 + l];
        }
        __syncthreads();
    }
    // P6: output MLPs (final h in index 1). lanes 0..31 -> i-path, 128..159 -> c-path
    {
        const bool actM = (tid < 32) || (tid >= 128 && tid < 160);
        const int g2 = (tid >= 128) ? 1 : 0;
        const int l = tid & 31;
        if (actM) {
            const float* w1 = g2 ? cm_w1 : im_w1;
            const float* b1 = g2 ? cm_b1 : im_b1;
            const float* hP = g2 ? &hC[1][0] : &hI[1][0];
            float a = b1[l];
#pragma unroll
            for (int d = 0; d < 32; d++) a = fmaf(hP[d], w1[d * 32 + l], a);
            afL[g2][l] = tanhf(a);
        }
        __syncthreads();
        if (actM) {
            const float* w2 = g2 ? cm_w2 : im_w2;
            const float* b2 = g2 ? cm_b2 : im_b2;
            float o = b2[l];
#pragma unroll
            for (int d = 0; d < 32; d++) o = fmaf(afL[g2][d], w2[d * 32 + l], o);
            (g2 ? z2fL : z1fL)[l] = o;
        }
        if (tid < 32) ocs[tid] = x1[b * 32 + tid];
    }
    __syncthreads();
    // P7: wgen  w[ly][kk] = clip(z1f.hw1) + z2f.hw2
    {
        const int kk = tid;
#pragma unroll
        for (int ly = 0; ly < LL; ly++) {
            float a = hb1[ly * 256 + kk], c = hb2[ly * 256 + kk];
            const float* h1 = hw1 + ly * 8192 + kk;
            const float* h2 = hw2 + ly * 8192 + kk;
#pragma unroll
            for (int d = 0; d < 32; d++) {
                a = fmaf(z1fL[d], h1[d * 256], a);
                c = fmaf(z2fL[d], h2[d * 256], c);
            }
            a = fminf(fmaxf(a, -NORMC), NORMC);
            wW[ly * 256 + kk] = a + c;
        }
    }
    __syncthreads();
    // P8: apply
#pragma unroll
    for (int i = 0; i < LL; i++) {
        if (tid < 16) {
            float a = lin_b[i * 16 + tid];
#pragma unroll
            for (int u = 0; u < 32; u++) a = fmaf(ocs[u], lin_w[i * 512 + u * 16 + tid], a);
            t1s[tid] = a;
        }
        __syncthreads();
        if (tid < 16) {
            float a = 0.f;
#pragma unroll
            for (int k = 0; k < 16; k++) a = fmaf(t1s[k], wW[i * 256 + k * 16 + tid], a);
            t2s[tid] = a;
        }
        __syncthreads();
        if (tid < 32) {
            float a = lout_b[i * 32 + tid];
#pragma unroll
            for (int k = 0; k < 16; k++) a = fmaf(t2s[k], lout_w[i * 512 + k * 32 + tid], a);
            ocs[tid] = a;
        }
        __syncthreads();
    }
    if (tid < 32) out[(size_t)b * 32 + tid] = ocs[tid];
    // P9: loss finalize via ticket
    if (tid == 0) {
        __threadfence();
        unsigned int old = atomicAdd(cnt, 1u);
        if (old == B - 1) {
            float tot = atomicAdd(loss_sum, 0.0f);
            out[B * UU] = tot * (1.0f / (float)(B * S * D));
        }
    }
}

extern "C" void kernel_launch(void* const* d_in, const int* in_sizes, int n_in,
                              void* d_out, int out_size, void* d_ws, size_t ws_size,
                              hipStream_t stream) {
    const float* x1     = (const float*)d_in[0];
    const float* z1     = (const float*)d_in[1];
    const float* z2     = (const float*)d_in[3];
    const float* embd   = (const float*)d_in[4];
    const float* dec_w1 = (const float*)d_in[5];
    const float* dec_b1 = (const float*)d_in[6];
    const float* dec_w2 = (const float*)d_in[7];
    const float* dec_b2 = (const float*)d_in[8];
    const float* i_wih  = (const float*)d_in[9];
    const float* i_whh  = (const float*)d_in[10];
    const float* i_bih  = (const float*)d_in[11];
    const float* i_bhh  = (const float*)d_in[12];
    const float* c_wih  = (const float*)d_in[13];
    const float* c_whh  = (const float*)d_in[14];
    const float* c_bih  = (const float*)d_in[15];
    const float* c_bhh  = (const float*)d_in[16];
    const float* im_w1  = (const float*)d_in[17];
    const float* im_b1  = (const float*)d_in[18];
    const float* im_w2  = (const float*)d_in[19];
    const float* im_b2  = (const float*)d_in[20];
    const float* cm_w1  = (const float*)d_in[21];
    const float* cm_b1  = (const float*)d_in[22];
    const float* cm_w2  = (const float*)d_in[23];
    const float* cm_b2  = (const float*)d_in[24];
    const float* hw1    = (const float*)d_in[25];
    const float* hb1    = (const float*)d_in[26];
    const float* hw2    = (const float*)d_in[27];
    const float* hb2    = (const float*)d_in[28];
    const float* lin_w  = (const float*)d_in[29];
    const float* lin_b  = (const float*)d_in[30];
    const float* lout_w = (const float*)d_in[31];
    const float* lout_b = (const float*)d_in[32];

    // workspace layout (floats)
    float* wsf      = (float*)d_ws;
    float* loss_sum = wsf;                        // [0]
    unsigned int* cnt = (unsigned int*)(wsf + 1); // [1]
    float* tn       = wsf + 64;                   // VPAD -> 10304
    float2* pbsv    = (float2*)(wsf + 10304);     // NROWS*NSLICE float2 = 256000 f -> 266304
    unsigned short* Eh = (unsigned short*)(wsf + 266304);  // 163840 f -> 430144
    unsigned short* El = (unsigned short*)(wsf + 430144);  // -> 593984
    unsigned short* Qh = (unsigned short*)(wsf + 593984);  // 204800 f -> 798784
    unsigned short* Ql = (unsigned short*)(wsf + 798784);  // -> 1003584 (~4.0 MB)

    k_prep<<<(VPAD * 4 + 4 * NROWS + 255) / 256, 256, 0, stream>>>(embd, z1, Eh, El, Qh, Ql,
                                                                   tn, loss_sum, cnt);
    k_vq<<<(NROWS / VQ_RB) * NSLICE, 256, 0, stream>>>((const short*)Qh, (const short*)Ql,
                                                       (const short*)Eh, (const short*)El, tn, pbsv);
    k_fused<<<B, 256, 0, stream>>>(x1, z2, embd, pbsv,
                                   dec_w1, dec_b1, dec_w2, dec_b2,
                                   i_wih, i_whh, i_bih, i_bhh,
                                   c_wih, c_whh, c_bih, c_bhh,
                                   im_w1, im_b1, im_w2, im_b2,
                                   cm_w1, cm_b1, cm_w2, cm_b2,
                                   hw1, hb1, hw2, hb2,
                                   lin_w, lin_b, lout_w, lout_b,
                                   loss_sum, cnt, (float*)d_out);
}